// Round 3
// baseline (425.090 us; speedup 1.0000x reference)
//
#include <hip/hip_runtime.h>

#define N_NODES 50000
#define N_EDGES 800000
#define D 64
#define RANGE 196                       // nodes owned per block; 256 blocks cover 50176
#define NBLK 256
#define SCAN_THREADS 1024
#define NWAVES (SCAN_THREADS / 64)
#define NCHUNKS ((N_EDGES + 511) / 512) // 1563 chunks of 512 edges
#define QCAP 128                        // per-wave queue; qn<=63 pre-push + <=64 per k-slot

// ---------------------------------------------------------------------------
// K0: pack node indices to u16 (ids < 65536) — halves all scan traffic
// ---------------------------------------------------------------------------
__global__ __launch_bounds__(256) void pack_kernel(const int* __restrict__ s,
                                                   const int* __restrict__ r,
                                                   ushort* __restrict__ s16,
                                                   ushort* __restrict__ r16) {
    int i = blockIdx.x * 256 + threadIdx.x;   // one group of 4 edges
    if (i * 4 >= N_EDGES) return;
    int4 sv = ((const int4*)s)[i];
    int4 rv = ((const int4*)r)[i];
    ushort4 so, ro;
    so.x = (ushort)sv.x; so.y = (ushort)sv.y; so.z = (ushort)sv.z; so.w = (ushort)sv.w;
    ro.x = (ushort)rv.x; ro.y = (ushort)rv.y; ro.z = (ushort)rv.z; ro.w = (ushort)rv.w;
    ((ushort4*)s16)[i] = so;
    ((ushort4*)r16)[i] = ro;
}

// ---------------------------------------------------------------------------
// K1: sender-degree scale via owner-computes range scan (LDS histogram,
// no global atomics). sscale[n] = rsqrt(1 + #edges with sender==n).
// ---------------------------------------------------------------------------
__global__ __launch_bounds__(SCAN_THREADS) void sdeg_kernel(
        const ushort* __restrict__ s16, float* __restrict__ sscale) {
    __shared__ int hist[RANGE];
    const int tid = threadIdx.x, lane = tid & 63, wv = tid >> 6;
    const int base = blockIdx.x * RANGE;
    for (int i = tid; i < RANGE; i += SCAN_THREADS) hist[i] = 0;
    __syncthreads();

    for (int c = wv; c < NCHUNKS; c += NWAVES) {
        int eb = c * 512 + lane * 8;
        if (eb < N_EDGES) {
            uint4 u = *(const uint4*)(s16 + eb);
            unsigned v[8] = {u.x & 0xffffu, u.x >> 16, u.y & 0xffffu, u.y >> 16,
                             u.z & 0xffffu, u.z >> 16, u.w & 0xffffu, u.w >> 16};
            #pragma unroll
            for (int k = 0; k < 8; ++k) {
                unsigned sl = v[k] - (unsigned)base;
                if (sl < RANGE) atomicAdd(&hist[sl], 1);
            }
        }
    }
    __syncthreads();
    for (int i = tid; i < RANGE; i += SCAN_THREADS) {
        int n = base + i;
        if (n < N_NODES) sscale[n] = rsqrtf((float)(hist[i] + 1));
    }
}

// ---------------------------------------------------------------------------
// K2: h = (x @ W^T + b) * sscale[n]. Wave per node, lane = out channel.
// ---------------------------------------------------------------------------
__global__ __launch_bounds__(256) void linear_kernel(
        const float* __restrict__ x, const float* __restrict__ w,
        const float* __restrict__ bias, const float* __restrict__ sscale,
        float* __restrict__ h) {
    const int lane = threadIdx.x & 63;
    const int wid = blockIdx.x * 4 + (threadIdx.x >> 6);
    const int nwaves = gridDim.x * 4;

    float4 wreg[16];
    #pragma unroll
    for (int i = 0; i < 16; ++i) wreg[i] = ((const float4*)w)[lane * 16 + i];
    const float bo = bias[lane];

    for (int n = wid; n < N_NODES; n += nwaves) {
        const float4* xr = (const float4*)(x + n * D);
        float acc = bo;
        #pragma unroll
        for (int i = 0; i < 16; ++i) {
            float4 xv = xr[i];
            acc += xv.x * wreg[i].x + xv.y * wreg[i].y
                 + xv.z * wreg[i].z + xv.w * wreg[i].w;
        }
        h[n * D + lane] = acc * sscale[n];
    }
}

// ---------------------------------------------------------------------------
// K3: fused scatter via owner-computes. Block owns RANGE nodes in an LDS
// fp32 tile; scans all receivers (u16), ballot-compacts hits into per-wave
// queues, processes queued edges wave-wide (coalesced h-row gather ->
// LDS fp32 atomic add), counts rdeg in LDS, finalizes with self-term +
// rsqrt + leaky-relu.
// ---------------------------------------------------------------------------
__global__ __launch_bounds__(SCAN_THREADS) void scatter_kernel(
        const ushort* __restrict__ s16, const ushort* __restrict__ r16,
        const float* __restrict__ h, float* __restrict__ out) {
    __shared__ float acc[RANGE * D];            // 50176 B
    __shared__ int rdeg[RANGE];                 //   784 B
    __shared__ int q[NWAVES][QCAP];             //  8192 B
    const int tid = threadIdx.x, lane = tid & 63, wv = tid >> 6;
    const int base = blockIdx.x * RANGE;

    for (int i = tid; i < RANGE * D; i += SCAN_THREADS) acc[i] = 0.0f;
    for (int i = tid; i < RANGE; i += SCAN_THREADS) rdeg[i] = 0;
    __syncthreads();

    const unsigned long long mlt = (1ull << lane) - 1ull;
    int qn = 0;

    for (int c = wv; c < NCHUNKS; c += NWAVES) {
        int eb = c * 512 + lane * 8;
        unsigned v[8];
        if (eb < N_EDGES) {
            uint4 u = *(const uint4*)(r16 + eb);
            v[0] = u.x & 0xffffu; v[1] = u.x >> 16;
            v[2] = u.y & 0xffffu; v[3] = u.y >> 16;
            v[4] = u.z & 0xffffu; v[5] = u.z >> 16;
            v[6] = u.w & 0xffffu; v[7] = u.w >> 16;
        } else {
            #pragma unroll
            for (int k = 0; k < 8; ++k) v[k] = 0x7fffffffu;  // never in range
        }
        #pragma unroll
        for (int k = 0; k < 8; ++k) {
            unsigned rl = v[k] - (unsigned)base;
            bool hit = rl < RANGE;
            unsigned long long m = __ballot(hit);
            if (m) {
                int rank = __popcll(m & mlt);
                if (hit) {
                    q[wv][qn + rank] = (eb + k) | ((int)rl << 20);  // e<2^20, rl<2^8
                    atomicAdd(&rdeg[rl], 1);
                }
                qn += (int)__popcll(m);
                if (qn >= 64) {                 // drain one full chunk of 64 edges
                    qn -= 64;
                    int pv = q[wv][qn + lane];
                    int e  = pv & 0xFFFFF;
                    int rl2 = pv >> 20;
                    int se = (int)s16[e];
                    #pragma unroll 8
                    for (int t = 0; t < 64; ++t) {
                        int seb = __shfl(se, t);
                        int rlb = __shfl(rl2, t);
                        atomicAdd(&acc[rlb * D + lane], h[seb * D + lane]);
                    }
                }
            }
        }
    }
    // tail drain (< 64 edges left in this wave's queue)
    if (qn > 0) {
        int pv = q[wv][lane < qn ? lane : 0];
        int e  = pv & 0xFFFFF;
        int rl2 = pv >> 20;
        int se = (int)s16[e];
        for (int t = 0; t < qn; ++t) {
            int seb = __shfl(se, t);
            int rlb = __shfl(rl2, t);
            atomicAdd(&acc[rlb * D + lane], h[seb * D + lane]);
        }
    }
    __syncthreads();

    // finalize: self-term + receiver rsqrt + leaky-relu, coalesced store
    for (int i = tid; i < RANGE * D; i += SCAN_THREADS) {
        int nl = i >> 6;
        int n = base + nl;
        if (n < N_NODES) {
            int d = i & 63;
            float vv = (acc[i] + h[n * D + d]) * rsqrtf((float)(rdeg[nl] + 1));
            out[n * D + d] = vv > 0.0f ? vv : 0.01f * vv;
        }
    }
}

// ---------------------------------------------------------------------------
extern "C" void kernel_launch(void* const* d_in, const int* in_sizes, int n_in,
                              void* d_out, int out_size, void* d_ws, size_t ws_size,
                              hipStream_t stream) {
    const float* x       = (const float*)d_in[0];
    const int*   senders = (const int*)d_in[1];
    const int*   recvs   = (const int*)d_in[2];
    const float* weight  = (const float*)d_in[3];
    const float* bias    = (const float*)d_in[4];
    float* out = (float*)d_out;

    // workspace layout (256B-aligned chunks)
    char* p = (char*)d_ws;
    float*  h      = (float*)p;   p += (size_t)N_NODES * D * 4;   // 12.8 MB
    float*  sscale = (float*)p;   p += (size_t)N_NODES * 4;       // 200 KB
    ushort* s16    = (ushort*)p;  p += (size_t)N_EDGES * 2;       // 1.6 MB
    ushort* r16    = (ushort*)p;  p += (size_t)N_EDGES * 2;       // 1.6 MB

    hipLaunchKernelGGL(pack_kernel, dim3((N_EDGES / 4 + 255) / 256), dim3(256), 0, stream,
                       senders, recvs, s16, r16);
    hipLaunchKernelGGL(sdeg_kernel, dim3(NBLK), dim3(SCAN_THREADS), 0, stream,
                       s16, sscale);
    hipLaunchKernelGGL(linear_kernel, dim3(1024), dim3(256), 0, stream,
                       x, weight, bias, sscale, h);
    hipLaunchKernelGGL(scatter_kernel, dim3(NBLK), dim3(SCAN_THREADS), 0, stream,
                       s16, r16, h, out);
}

// Round 4
// 205.002 us; speedup vs baseline: 2.0736x; 2.0736x over previous
//
#include <hip/hip_runtime.h>

#define N_NODES 50000
#define N_EDGES 800000
#define D 64
#define NBLK 256
#define RANGE 196            // 196*256 = 50176 >= 50000
#define SCAN_T 1024
#define NWAVES 16
#define NCHUNKS 1563         // ceil(800000/512)

// ---------------------------------------------------------------------------
// K0: pack node indices to u16 (ids < 65536) — halves all per-block scan traffic
// ---------------------------------------------------------------------------
__global__ __launch_bounds__(256) void pack_kernel(const int* __restrict__ s,
                                                   const int* __restrict__ r,
                                                   ushort* __restrict__ s16,
                                                   ushort* __restrict__ r16) {
    int i = blockIdx.x * 256 + threadIdx.x;   // one group of 4 edges
    if (i >= N_EDGES / 4) return;
    int4 sv = ((const int4*)s)[i];
    int4 rv = ((const int4*)r)[i];
    ushort4 so, ro;
    so.x = (ushort)sv.x; so.y = (ushort)sv.y; so.z = (ushort)sv.z; so.w = (ushort)sv.w;
    ro.x = (ushort)rv.x; ro.y = (ushort)rv.y; ro.z = (ushort)rv.z; ro.w = (ushort)rv.w;
    ((ushort4*)s16)[i] = so;
    ((ushort4*)r16)[i] = ro;
}

// ---------------------------------------------------------------------------
// K1: owner-computes degree histograms (no global atomics).
// Block owns RANGE nodes; scans full edge list; writes sscale, rdeg, bsum.
// ---------------------------------------------------------------------------
__global__ __launch_bounds__(SCAN_T) void hist_kernel(
        const ushort* __restrict__ s16, const ushort* __restrict__ r16,
        float* __restrict__ sscale, int* __restrict__ rdeg, int* __restrict__ bsum) {
    __shared__ int sh[RANGE];
    __shared__ int rh[RANGE];
    __shared__ int wsum[NWAVES];
    const int tid = threadIdx.x, lane = tid & 63, wv = tid >> 6;
    const unsigned base = blockIdx.x * RANGE;

    for (int i = tid; i < RANGE; i += SCAN_T) { sh[i] = 0; rh[i] = 0; }
    __syncthreads();

    for (int c = wv; c < NCHUNKS; c += NWAVES) {
        int eb = c * 512 + lane * 8;
        if (eb < N_EDGES) {
            uint4 us = *(const uint4*)(s16 + eb);
            uint4 ur = *(const uint4*)(r16 + eb);
            unsigned sv[8] = {us.x & 0xffffu, us.x >> 16, us.y & 0xffffu, us.y >> 16,
                              us.z & 0xffffu, us.z >> 16, us.w & 0xffffu, us.w >> 16};
            unsigned rv[8] = {ur.x & 0xffffu, ur.x >> 16, ur.y & 0xffffu, ur.y >> 16,
                              ur.z & 0xffffu, ur.z >> 16, ur.w & 0xffffu, ur.w >> 16};
            #pragma unroll
            for (int k = 0; k < 8; ++k) {
                unsigned sl = sv[k] - base;
                if (sl < RANGE) atomicAdd(&sh[sl], 1);
                unsigned rl = rv[k] - base;
                if (rl < RANGE) atomicAdd(&rh[rl], 1);
            }
        }
    }
    __syncthreads();

    for (int i = tid; i < RANGE; i += SCAN_T) {
        int n = (int)base + i;
        if (n < N_NODES) {
            sscale[n] = rsqrtf((float)(sh[i] + 1));   // +1 = self edge
            rdeg[n]   = rh[i];                        // real in-degree (no self)
        }
    }
    // block total of rh -> bsum
    int tot = 0;
    for (int i = tid; i < RANGE; i += SCAN_T) {
        int n = (int)base + i;
        tot += (n < N_NODES) ? rh[i] : 0;
    }
    #pragma unroll
    for (int o = 32; o > 0; o >>= 1) tot += __shfl_down(tot, o);
    if (lane == 0) wsum[wv] = tot;
    __syncthreads();
    if (tid == 0) {
        int s = 0;
        for (int k = 0; k < NWAVES; ++k) s += wsum[k];
        bsum[blockIdx.x] = s;
    }
}

// ---------------------------------------------------------------------------
// K2: exclusive scan of the 256 block sums (single block)
// ---------------------------------------------------------------------------
__global__ __launch_bounds__(256) void scan_kernel(int* __restrict__ bsum) {
    __shared__ int sc[256];
    int t = threadIdx.x;
    int v = bsum[t];
    sc[t] = v;
    __syncthreads();
    for (int o = 1; o < 256; o <<= 1) {
        int u = (t >= o) ? sc[t - o] : 0;
        __syncthreads();
        sc[t] += u;
        __syncthreads();
    }
    bsum[t] = sc[t] - v;   // exclusive
}

// ---------------------------------------------------------------------------
// K3: owner-computes CSR fill. Local scan of owned rdeg -> LDS cursors,
// then scan full edge list; in-range receivers append sender (u16) via
// LDS-atomic cursor. Also writes rowoff.
// ---------------------------------------------------------------------------
__global__ __launch_bounds__(SCAN_T) void fill_kernel(
        const ushort* __restrict__ s16, const ushort* __restrict__ r16,
        const int* __restrict__ rdeg, const int* __restrict__ bsum,
        int* __restrict__ rowoff, ushort* __restrict__ csr16) {
    __shared__ int cur[RANGE];
    __shared__ int sc[256];
    const int tid = threadIdx.x, lane = tid & 63, wv = tid >> 6;
    const unsigned base = blockIdx.x * RANGE;

    int v = 0;
    if (tid < 256) {
        int n = (int)base + tid;
        v = (tid < RANGE && n < N_NODES) ? rdeg[n] : 0;
        sc[tid] = v;
    }
    __syncthreads();
    for (int o = 1; o < 256; o <<= 1) {
        int u = 0;
        if (tid < 256 && tid >= o) u = sc[tid - o];
        __syncthreads();
        if (tid < 256) sc[tid] += u;
        __syncthreads();
    }
    if (tid < RANGE) {
        int n = (int)base + tid;
        if (n < N_NODES) {
            int ro = bsum[blockIdx.x] + sc[tid] - v;  // exclusive global offset
            rowoff[n] = ro;
            cur[tid] = ro;
        }
    }
    __syncthreads();

    for (int c = wv; c < NCHUNKS; c += NWAVES) {
        int eb = c * 512 + lane * 8;
        if (eb < N_EDGES) {
            uint4 ur = *(const uint4*)(r16 + eb);
            uint4 us = *(const uint4*)(s16 + eb);
            unsigned rv[8] = {ur.x & 0xffffu, ur.x >> 16, ur.y & 0xffffu, ur.y >> 16,
                              ur.z & 0xffffu, ur.z >> 16, ur.w & 0xffffu, ur.w >> 16};
            unsigned sv[8] = {us.x & 0xffffu, us.x >> 16, us.y & 0xffffu, us.y >> 16,
                              us.z & 0xffffu, us.z >> 16, us.w & 0xffffu, us.w >> 16};
            #pragma unroll
            for (int k = 0; k < 8; ++k) {
                unsigned rl = rv[k] - base;
                if (rl < RANGE) {
                    int pos = atomicAdd(&cur[rl], 1);
                    csr16[pos] = (ushort)sv[k];
                }
            }
        }
    }
}

// ---------------------------------------------------------------------------
// K4: h = (x @ W^T + b) * sscale[n]. Wave per node batch, lane = out channel.
// 4 partial accumulators break the 64-FMA serial chain.
// ---------------------------------------------------------------------------
__global__ __launch_bounds__(256) void linear_kernel(
        const float* __restrict__ x, const float* __restrict__ w,
        const float* __restrict__ bias, const float* __restrict__ sscale,
        float* __restrict__ h) {
    const int lane = threadIdx.x & 63;
    const int wid = blockIdx.x * 4 + (threadIdx.x >> 6);
    const int nwaves = gridDim.x * 4;

    float4 wreg[16];
    #pragma unroll
    for (int i = 0; i < 16; ++i) wreg[i] = ((const float4*)w)[lane * 16 + i];
    const float bo = bias[lane];

    for (int n = wid; n < N_NODES; n += nwaves) {
        const float4* xr = (const float4*)(x + n * D);
        float a0 = 0.f, a1 = 0.f, a2 = 0.f, a3 = 0.f;
        #pragma unroll
        for (int i = 0; i < 16; i += 4) {
            float4 x0 = xr[i], x1 = xr[i + 1], x2 = xr[i + 2], x3 = xr[i + 3];
            a0 += x0.x * wreg[i].x + x0.y * wreg[i].y + x0.z * wreg[i].z + x0.w * wreg[i].w;
            a1 += x1.x * wreg[i+1].x + x1.y * wreg[i+1].y + x1.z * wreg[i+1].z + x1.w * wreg[i+1].w;
            a2 += x2.x * wreg[i+2].x + x2.y * wreg[i+2].y + x2.z * wreg[i+2].z + x2.w * wreg[i+2].w;
            a3 += x3.x * wreg[i+3].x + x3.y * wreg[i+3].y + x3.z * wreg[i+3].z + x3.w * wreg[i+3].w;
        }
        h[n * D + lane] = (bo + (a0 + a1) + (a2 + a3)) * sscale[n];
    }
}

// ---------------------------------------------------------------------------
// K5: gather-accumulate per receiver + self-term + rsqrt + leaky-relu.
// Wave per node; neighbor loop unrolled x8 so loads batch under one waitcnt.
// ---------------------------------------------------------------------------
__global__ __launch_bounds__(256) void gather_kernel(
        const float* __restrict__ h, const int* __restrict__ rowoff,
        const int* __restrict__ rdeg, const ushort* __restrict__ csr16,
        float* __restrict__ out) {
    const int lane = threadIdx.x & 63;
    const int n = blockIdx.x * 4 + (threadIdx.x >> 6);
    if (n >= N_NODES) return;

    float acc = h[n * D + lane];           // self-edge contribution
    const int base = rowoff[n];
    const int cnt = rdeg[n];

    for (int j0 = 0; j0 < cnt; j0 += 64) {
        int m = cnt - j0; if (m > 64) m = 64;
        int my = (lane < m) ? (int)csr16[base + j0 + lane] : 0;
        int t = 0;
        for (; t + 8 <= m; t += 8) {
            float a0 = h[__shfl(my, t + 0) * D + lane];
            float a1 = h[__shfl(my, t + 1) * D + lane];
            float a2 = h[__shfl(my, t + 2) * D + lane];
            float a3 = h[__shfl(my, t + 3) * D + lane];
            float a4 = h[__shfl(my, t + 4) * D + lane];
            float a5 = h[__shfl(my, t + 5) * D + lane];
            float a6 = h[__shfl(my, t + 6) * D + lane];
            float a7 = h[__shfl(my, t + 7) * D + lane];
            acc += ((a0 + a1) + (a2 + a3)) + ((a4 + a5) + (a6 + a7));
        }
        for (; t < m; ++t) acc += h[__shfl(my, t) * D + lane];
    }
    float vv = acc * rsqrtf((float)(cnt + 1));
    out[n * D + lane] = vv > 0.0f ? vv : 0.01f * vv;
}

// ---------------------------------------------------------------------------
extern "C" void kernel_launch(void* const* d_in, const int* in_sizes, int n_in,
                              void* d_out, int out_size, void* d_ws, size_t ws_size,
                              hipStream_t stream) {
    const float* x       = (const float*)d_in[0];
    const int*   senders = (const int*)d_in[1];
    const int*   recvs   = (const int*)d_in[2];
    const float* weight  = (const float*)d_in[3];
    const float* bias    = (const float*)d_in[4];
    float* out = (float*)d_out;

    // workspace layout (256B-aligned chunks)
    char* p = (char*)d_ws;
    auto take = [&](size_t bytes) { char* q = p; p += (bytes + 255) & ~(size_t)255; return q; };
    float*  h      = (float*)take((size_t)N_NODES * D * 4);   // 12.8 MB
    float*  sscale = (float*)take((size_t)N_NODES * 4);
    int*    rdeg   = (int*)take((size_t)N_NODES * 4);
    int*    rowoff = (int*)take((size_t)N_NODES * 4);
    int*    bsum   = (int*)take(NBLK * 4);
    ushort* s16    = (ushort*)take((size_t)N_EDGES * 2);
    ushort* r16    = (ushort*)take((size_t)N_EDGES * 2);
    ushort* csr16  = (ushort*)take((size_t)N_EDGES * 2);

    hipLaunchKernelGGL(pack_kernel, dim3((N_EDGES / 4 + 255) / 256), dim3(256), 0, stream,
                       senders, recvs, s16, r16);
    hipLaunchKernelGGL(hist_kernel, dim3(NBLK), dim3(SCAN_T), 0, stream,
                       s16, r16, sscale, rdeg, bsum);
    hipLaunchKernelGGL(scan_kernel, dim3(1), dim3(256), 0, stream, bsum);
    hipLaunchKernelGGL(fill_kernel, dim3(NBLK), dim3(SCAN_T), 0, stream,
                       s16, r16, rdeg, bsum, rowoff, csr16);
    hipLaunchKernelGGL(linear_kernel, dim3(1024), dim3(256), 0, stream,
                       x, weight, bias, sscale, h);
    hipLaunchKernelGGL(gather_kernel, dim3((N_NODES + 3) / 4), dim3(256), 0, stream,
                       h, rowoff, rdeg, csr16, out);
}